// Round 15
// baseline (303.685 us; speedup 1.0000x reference)
//
#include <hip/hip_runtime.h>

// VectorQuantizer on MI355X — round 15: vq_post 32-pt blocks (4 blocks/CU),
// prep+z2 merged into vq_pre. Screen = r14 (reg-dbuf B prefetch).
// z: (64,256,32,32) f32; emb: (1024,256) f32.
// out (f32): [0,16777216) z_q_out | [16777216] loss | [16777217,+65536) indices
//
// ws layout (bytes):
//   0        double   loss_acc                 (memset 0)
//   262208   float    e2[1024]                 (numpy-pairwise fp32)
//   266304   float    z2[65536]                (numpy-pairwise fp32)
//   528448   int      gcnt[65536]
//   790592   ushort   gcand[65536*16]
//   2887744  _Float16 Ef[1024*256]             (f16 RNE copy of emb)

typedef _Float16 f16x8 __attribute__((ext_vector_type(8)));
typedef float f32x4 __attribute__((ext_vector_type(4)));

#define VQ_W 1.5e-3f
#define SCR_LDS_BYTES 35328
#define POST_LDS_BYTES 33664

// fl32(v*v) with a barrier so the product cannot be contracted into a later add.
__device__ __forceinline__ float sq_rnd(float v) {
  float y = v * v;
  asm volatile("" : "+v"(y));
  return y;
}

// numpy pairwise_sum over 256 fp32 squared terms (8-accumulator blocks of 128).
__device__ float np_pw256_sq(const float* base, int stride) {
  float tot0, tot1;
  {
    const float* a = base;
    float r[8];
    #pragma unroll
    for (int j = 0; j < 8; ++j) r[j] = sq_rnd(a[j * stride]);
    #pragma unroll 1
    for (int i = 8; i < 128; i += 8) {
      #pragma unroll
      for (int j = 0; j < 8; ++j) r[j] += sq_rnd(a[(i + j) * stride]);
    }
    tot0 = ((r[0] + r[1]) + (r[2] + r[3])) + ((r[4] + r[5]) + (r[6] + r[7]));
  }
  {
    const float* a = base + 128 * stride;
    float r[8];
    #pragma unroll
    for (int j = 0; j < 8; ++j) r[j] = sq_rnd(a[j * stride]);
    #pragma unroll 1
    for (int i = 8; i < 128; i += 8) {
      #pragma unroll
      for (int j = 0; j < 8; ++j) r[j] += sq_rnd(a[(i + j) * stride]);
    }
    tot1 = ((r[0] + r[1]) + (r[2] + r[3])) + ((r[4] + r[5]) + (r[6] + r[7]));
  }
  return tot0 + tot1;
}

// Fused preprocessing: blocks [0,1024) = emb->f16 + e2 (r3-verified);
// blocks [1024,5120) = z2 chain-split (r11-verified, bit-exact np order).
__global__ __launch_bounds__(256) void vq_pre(const float* __restrict__ emb,
                                              const float* __restrict__ z,
                                              _Float16* __restrict__ Ef,
                                              float* __restrict__ e2,
                                              float* __restrict__ z2) {
  __shared__ float sm[256];
  const int tid = threadIdx.x;
  if (blockIdx.x < 1024) {
    const int g = blockIdx.x * 256 + tid;  // 0..262143
    Ef[g] = (_Float16)emb[g];              // RNE v_cvt_f16_f32
    if (g < 1024) e2[g] = np_pw256_sq(emb + g * 256, 1);
    return;
  }
  const int blk = blockIdx.x - 1024;       // 0..4095
  const int p = tid & 15;
  const int c = tid >> 4;
  const int n0 = blk * 16;
  const int n = n0 + p;
  const int bb = n >> 10, hw = n & 1023;
  const float* zp = z + bb * 262144 + hw;
  const int dbase = (c >> 3) * 128 + (c & 7);
  float r = sq_rnd(zp[dbase * 1024]);
  #pragma unroll
  for (int i = 1; i < 16; ++i) r += sq_rnd(zp[(dbase + 8 * i) * 1024]);
  sm[c * 16 + p] = r;
  __syncthreads();
  if (tid < 16) {
    const int pp = tid;
    float h0[8], h1[8];
    #pragma unroll
    for (int j = 0; j < 8; ++j) {
      h0[j] = sm[j * 16 + pp];
      h1[j] = sm[(8 + j) * 16 + pp];
    }
    const float tot0 = ((h0[0] + h0[1]) + (h0[2] + h0[3])) +
                       ((h0[4] + h0[5]) + (h0[6] + h0[7]));
    const float tot1 = ((h1[0] + h1[1]) + (h1[2] + h1[3])) +
                       ((h1[4] + h1[5]) + (h1[6] + h1[7]));
    z2[n0 + pp] = tot0 + tot1;
  }
}

// Screening v7 (r14): 64 pts/block, 256 thr, B direct from L2 with register
// double-buffered prefetch (phase p+1's B issued before phase p's MFMAs).
// Chunk epilogue: exact prefix-min via one barrier (r9-verified superset).
__global__ __launch_bounds__(256, 4) void vq_screen(
    const float* __restrict__ z, const _Float16* __restrict__ Ef,
    const float* __restrict__ e2, const float* __restrict__ z2,
    int* __restrict__ gcnt, unsigned short* __restrict__ gcand) {
  extern __shared__ __align__(16) char smem[];
  // [0,32768) A; 32768 runminU[64]; 33024 cnt[64]; 33280 cand[64][16]
  unsigned* runminU = (unsigned*)(smem + 32768);
  int* cnt = (int*)(smem + 33024);
  unsigned short* cand = (unsigned short*)(smem + 33280);

  const int tid = threadIdx.x;
  const int blk = blockIdx.x;
  const int n0 = blk * 64;
  const int bb = blk >> 4;
  const int hw0 = (blk & 15) * 64;
  const float* zb = z + bb * 262144 + hw0;

  if (tid < 64) { runminU[tid] = 0x7F800000u; cnt[tid] = 0; }

  {  // A stage: convert z tile to f16, swizzled rows
    const int p = tid & 63, dh = tid >> 6;
    #pragma unroll
    for (int dq = 0; dq < 8; ++dq) {
      const int d0 = dh * 64 + dq * 8;
      f16x8 hv;
      #pragma unroll
      for (int j = 0; j < 8; ++j) hv[j] = (_Float16)zb[(d0 + j) * 1024 + p];
      *(f16x8*)&smem[p * 512 + ((d0 * 2) ^ ((p & 7) * 16))] = hv;
    }
  }

  const int l = tid & 63;
  const int ln = l & 15;
  const int q = l >> 4;
  const int wc = tid >> 6;        // wave: codes wc*64 .. +63 per chunk
  const int xr = (l & 7) * 16;

  float z2r[4][4];
  #pragma unroll
  for (int fi = 0; fi < 4; ++fi)
    #pragma unroll
    for (int rg = 0; rg < 4; ++rg)
      z2r[fi][rg] = z2[n0 + fi * 16 + q * 4 + rg];

  f32x4 acc[4][4];
  #pragma unroll
  for (int fi = 0; fi < 4; ++fi)
    #pragma unroll
    for (int fj = 0; fj < 4; ++fj) acc[fi][fj] = (f32x4){0.f, 0.f, 0.f, 0.f};

  __syncthreads();

  for (int cc = 0; cc < 4; ++cc) {
    const _Float16* Ebase = Ef + (cc * 256 + wc * 64 + ln) * 256 + q * 8;
    f16x8 bFb[2][4];
    #pragma unroll
    for (int fj = 0; fj < 4; ++fj)   // prologue: phase-0 B fragments
      bFb[0][fj] = *(const f16x8*)(Ebase + fj * 16 * 256);
    #pragma unroll
    for (int ph = 0; ph < 8; ++ph) {
      const int cur = ph & 1, nxt = cur ^ 1;
      if (ph < 7) {  // issue next phase's B loads before this phase's MFMAs
        #pragma unroll
        for (int fj = 0; fj < 4; ++fj)
          bFb[nxt][fj] = *(const f16x8*)(Ebase + fj * 16 * 256 + (ph + 1) * 32);
      }
      f16x8 aF[4];
      const int ab = (ph * 64 + q * 16) ^ xr;
      #pragma unroll
      for (int fi = 0; fi < 4; ++fi)
        aF[fi] = *(const f16x8*)&smem[(fi * 16 + ln) * 512 + ab];
      #pragma unroll
      for (int fi = 0; fi < 4; ++fi)
        #pragma unroll
        for (int fj = 0; fj < 4; ++fj)
          acc[fi][fj] = __builtin_amdgcn_mfma_f32_16x16x32_f16(
              aF[fi], bFb[cur][fj], acc[fi][fj], 0, 0, 0);
    }
    {  // chunk epilogue: exact prefix-min via one barrier
      const int cbase = cc * 256 + wc * 64 + ln;
      float e2v[4];
      #pragma unroll
      for (int fj = 0; fj < 4; ++fj) e2v[fj] = e2[cbase + fj * 16];
      #pragma unroll
      for (int fi = 0; fi < 4; ++fi) {
        #pragma unroll
        for (int rg = 0; rg < 4; ++rg) {
          float rm = 3.4e38f;
          #pragma unroll
          for (int fj = 0; fj < 4; ++fj)
            rm = fminf(rm, fmaf(-2.f, acc[fi][fj][rg], z2r[fi][rg] + e2v[fj]));
          rm = fminf(rm, __shfl_xor(rm, 1));
          rm = fminf(rm, __shfl_xor(rm, 2));
          rm = fminf(rm, __shfl_xor(rm, 4));
          rm = fminf(rm, __shfl_xor(rm, 8));
          if (ln == 0)
            atomicMin(&runminU[fi * 16 + q * 4 + rg], __float_as_uint(rm));
        }
      }
      __syncthreads();  // runminU now = true min over ALL codes up to chunk cc
      #pragma unroll
      for (int fi = 0; fi < 4; ++fi) {
        #pragma unroll
        for (int rg = 0; rg < 4; ++rg) {
          const int row = fi * 16 + q * 4 + rg;
          const float thr = __uint_as_float(runminU[row]) + VQ_W;
          #pragma unroll
          for (int fj = 0; fj < 4; ++fj) {
            const float sv = fmaf(-2.f, acc[fi][fj][rg], z2r[fi][rg] + e2v[fj]);
            if (sv <= thr) {
              const int slot = atomicAdd(&cnt[row], 1);
              if (slot < 16)
                cand[row * 16 + slot] = (unsigned short)(cbase + fj * 16);
            }
          }
        }
        #pragma unroll
        for (int fj = 0; fj < 4; ++fj) acc[fi][fj] = (f32x4){0.f, 0.f, 0.f, 0.f};
      }
    }
  }

  __syncthreads();
  if (tid < 64) gcnt[n0 + tid] = cnt[tid];
  {
    const int rr = tid >> 2, si = (tid & 3) * 4;
    *(uint2*)&gcand[(n0 + rr) * 16 + si] = *(const uint2*)&cand[rr * 16 + si];
  }
}

// vq_post v2: fused rescore + output + loss, 32 points/block (grid 2048),
// LDS 33.7KB -> 4 blocks/CU (16 waves). Phase R: z tile -> LDS (bit-exact f32),
// 8 threads/point rescore (r6-verified chain), u64 atomicMin merge.
// Phase O: gather 32 emb rows -> LDS (coalesced), transpose-read + coalesced
// z_q_out write + fp64 loss. Indices written in phase R.
__global__ __launch_bounds__(256) void vq_post(
    const float* __restrict__ z, const float* __restrict__ emb,
    const float* __restrict__ e2, const float* __restrict__ z2,
    const int* __restrict__ gcnt, const unsigned short* __restrict__ gcand,
    float* __restrict__ out, double* __restrict__ acc) {
  extern __shared__ __align__(16) char psmem[];
  // union @0: zt[32][257] f32 (32896B, phase R) | rows[32][260] f32 (33280B, phase O)
  // 33280 wid[32] int (128B) ; 33408 best[32] u64 (256B)
  float* zt = (float*)psmem;
  float* rows = (float*)psmem;
  int* wid = (int*)(psmem + 33280);
  unsigned long long* best = (unsigned long long*)(psmem + 33408);

  const int tid = threadIdx.x;
  const int w8 = tid >> 5;   // 0..7
  const int l = tid & 31;    // point 0..31
  const int n0 = blockIdx.x << 5;
  const int bb = n0 >> 10, hw0 = n0 & 1023;
  const int n = n0 + l;

  const int c = gcnt[n];
  const bool need = __any(c >= 2);  // wave-uniform: every wave sees l=0..31

  if (need) {  // stage z tile (f32 bit-exact), d = it*8 + w8
    const float* zb = z + bb * 262144 + hw0;
    #pragma unroll 8
    for (int it = 0; it < 32; ++it) {
      const int d = it * 8 + w8;
      zt[l * 257 + d] = zb[d * 1024 + l];
    }
  }
  if (tid < 32) best[tid] = ~0ULL;
  __syncthreads();

  if (need && c >= 2) {
    const float z2n = z2[n];
    const float* zrow = &zt[l * 257];
    if (c <= 16) {
      for (int s = w8; s < c; s += 8) {
        const int k = gcand[n * 16 + s];
        const float* ep = emb + k * 256;
        float a = 0.f;
        #pragma unroll 4
        for (int d = 0; d < 256; ++d) a = fmaf(zrow[d], ep[d], a);
        const float sv = fmaf(-2.f, a, z2n + e2[k]);
        const unsigned long long key =
            ((unsigned long long)__float_as_uint(sv) << 10) | (unsigned)k;
        atomicMin(&best[l], key);
      }
    } else {  // overflow fallback: exact full scan
      for (int k = w8; k < 1024; k += 8) {
        const float* ep = emb + k * 256;
        float a = 0.f;
        #pragma unroll 4
        for (int d = 0; d < 256; ++d) a = fmaf(zrow[d], ep[d], a);
        const float sv = fmaf(-2.f, a, z2n + e2[k]);
        const unsigned long long key =
            ((unsigned long long)__float_as_uint(sv) << 10) | (unsigned)k;
        atomicMin(&best[l], key);
      }
    }
  }
  __syncthreads();
  if (tid < 32) {
    const int cc = gcnt[n0 + tid];
    const int v = (cc == 1) ? (int)gcand[(n0 + tid) * 16]
                            : (int)(best[tid] & 1023ULL);
    wid[tid] = v;
    out[16777217 + n0 + tid] = (float)v;
  }
  __syncthreads();

  // Phase O: gather emb rows (coalesced within row), then transposed output.
  {
    const int l64 = tid & 63, wp = tid >> 6;
    #pragma unroll 4
    for (int rr = 0; rr < 8; ++rr) {
      const int r = rr * 4 + wp;
      const int idx = wid[r];
      const float4 ev = *(const float4*)&emb[idx * 256 + l64 * 4];
      *(float4*)&rows[r * 260 + l64 * 4] = ev;
    }
  }
  __syncthreads();

  const int zofs = bb * 262144 + hw0 + l;
  const float* zp = z + zofs;
  float* op = out + zofs;
  double ls = 0.0;
  #pragma unroll 2
  for (int i16 = 0; i16 < 8; ++i16) {
    const int d4 = w8 * 32 + i16 * 4;
    const float4 q4 = *(const float4*)&rows[l * 260 + d4];
    #pragma unroll
    for (int e = 0; e < 4; ++e) {
      const int d = d4 + e;
      const float zv = zp[d * 1024];
      const float qv = ((const float*)&q4)[e];
      float df = qv - zv;
      asm volatile("" : "+v"(df));
      op[d * 1024] = zv + df;  // fl(z + fl(z_q - z))
      ls += (double)df * df;
    }
  }
  #pragma unroll
  for (int off = 32; off > 0; off >>= 1) ls += __shfl_down(ls, off);
  if ((tid & 63) == 0) atomicAdd(acc, ls);
}

__global__ void vq_fin(const double* __restrict__ acc, float* __restrict__ out) {
  if (threadIdx.x == 0)
    out[16777216] = (float)(1.25 * (*acc) * (1.0 / 16777216.0));
}

extern "C" void kernel_launch(void* const* d_in, const int* in_sizes, int n_in,
                              void* d_out, int out_size, void* d_ws, size_t ws_size,
                              hipStream_t stream) {
  const float* z = (const float*)d_in[0];
  const float* emb = (const float*)d_in[1];
  float* out = (float*)d_out;
  char* ws = (char*)d_ws;
  double* acc = (double*)(ws);
  float* e2 = (float*)(ws + 262208);
  float* z2 = (float*)(ws + 266304);
  int* gcnt = (int*)(ws + 528448);
  unsigned short* gcand = (unsigned short*)(ws + 790592);
  _Float16* Ef = (_Float16*)(ws + 2887744);

  hipFuncSetAttribute(reinterpret_cast<const void*>(vq_screen),
                      hipFuncAttributeMaxDynamicSharedMemorySize, SCR_LDS_BYTES);
  hipFuncSetAttribute(reinterpret_cast<const void*>(vq_post),
                      hipFuncAttributeMaxDynamicSharedMemorySize, POST_LDS_BYTES);

  hipMemsetAsync(ws, 0, 64, stream);
  vq_pre<<<5120, 256, 0, stream>>>(emb, z, Ef, e2, z2);
  vq_screen<<<1024, 256, SCR_LDS_BYTES, stream>>>(z, Ef, e2, z2, gcnt, gcand);
  vq_post<<<2048, 256, POST_LDS_BYTES, stream>>>(z, emb, e2, z2, gcnt, gcand,
                                                 out, acc);
  vq_fin<<<1, 64, 0, stream>>>(acc, out);
}

// Round 16
// 290.812 us; speedup vs baseline: 1.0443x; 1.0443x over previous
//
#include <hip/hip_runtime.h>

// VectorQuantizer on MI355X — round 16: vq_post fully float4-vectorized
// (stage/gather/out all 16B VMEM; 24 VMEM instrs/thread vs 64+ scalar).
// z: (64,256,32,32) f32; emb: (1024,256) f32.
// out (f32): [0,16777216) z_q_out | [16777216] loss | [16777217,+65536) indices
//
// ws layout (bytes):
//   0        double   loss_acc                 (memset 0)
//   262208   float    e2[1024]                 (numpy-pairwise fp32)
//   266304   float    z2[65536]                (numpy-pairwise fp32)
//   528448   int      gcnt[65536]
//   790592   ushort   gcand[65536*16]
//   2887744  _Float16 Ef[1024*256]             (f16 RNE copy of emb)

typedef _Float16 f16x8 __attribute__((ext_vector_type(8)));
typedef float f32x4 __attribute__((ext_vector_type(4)));

#define VQ_W 1.5e-3f
#define SCR_LDS_BYTES 35328
#define POST_LDS_BYTES 33792

// fl32(v*v) with a barrier so the product cannot be contracted into a later add.
__device__ __forceinline__ float sq_rnd(float v) {
  float y = v * v;
  asm volatile("" : "+v"(y));
  return y;
}

// numpy pairwise_sum over 256 fp32 squared terms (8-accumulator blocks of 128).
__device__ float np_pw256_sq(const float* base, int stride) {
  float tot0, tot1;
  {
    const float* a = base;
    float r[8];
    #pragma unroll
    for (int j = 0; j < 8; ++j) r[j] = sq_rnd(a[j * stride]);
    #pragma unroll 1
    for (int i = 8; i < 128; i += 8) {
      #pragma unroll
      for (int j = 0; j < 8; ++j) r[j] += sq_rnd(a[(i + j) * stride]);
    }
    tot0 = ((r[0] + r[1]) + (r[2] + r[3])) + ((r[4] + r[5]) + (r[6] + r[7]));
  }
  {
    const float* a = base + 128 * stride;
    float r[8];
    #pragma unroll
    for (int j = 0; j < 8; ++j) r[j] = sq_rnd(a[j * stride]);
    #pragma unroll 1
    for (int i = 8; i < 128; i += 8) {
      #pragma unroll
      for (int j = 0; j < 8; ++j) r[j] += sq_rnd(a[(i + j) * stride]);
    }
    tot1 = ((r[0] + r[1]) + (r[2] + r[3])) + ((r[4] + r[5]) + (r[6] + r[7]));
  }
  return tot0 + tot1;
}

// Fused preprocessing: blocks [0,1024) = emb->f16 + e2 (r3-verified);
// blocks [1024,5120) = z2 chain-split (r11-verified, bit-exact np order).
__global__ __launch_bounds__(256) void vq_pre(const float* __restrict__ emb,
                                              const float* __restrict__ z,
                                              _Float16* __restrict__ Ef,
                                              float* __restrict__ e2,
                                              float* __restrict__ z2) {
  __shared__ float sm[256];
  const int tid = threadIdx.x;
  if (blockIdx.x < 1024) {
    const int g = blockIdx.x * 256 + tid;  // 0..262143
    Ef[g] = (_Float16)emb[g];              // RNE v_cvt_f16_f32
    if (g < 1024) e2[g] = np_pw256_sq(emb + g * 256, 1);
    return;
  }
  const int blk = blockIdx.x - 1024;       // 0..4095
  const int p = tid & 15;
  const int c = tid >> 4;
  const int n0 = blk * 16;
  const int n = n0 + p;
  const int bb = n >> 10, hw = n & 1023;
  const float* zp = z + bb * 262144 + hw;
  const int dbase = (c >> 3) * 128 + (c & 7);
  float r = sq_rnd(zp[dbase * 1024]);
  #pragma unroll
  for (int i = 1; i < 16; ++i) r += sq_rnd(zp[(dbase + 8 * i) * 1024]);
  sm[c * 16 + p] = r;
  __syncthreads();
  if (tid < 16) {
    const int pp = tid;
    float h0[8], h1[8];
    #pragma unroll
    for (int j = 0; j < 8; ++j) {
      h0[j] = sm[j * 16 + pp];
      h1[j] = sm[(8 + j) * 16 + pp];
    }
    const float tot0 = ((h0[0] + h0[1]) + (h0[2] + h0[3])) +
                       ((h0[4] + h0[5]) + (h0[6] + h0[7]));
    const float tot1 = ((h1[0] + h1[1]) + (h1[2] + h1[3])) +
                       ((h1[4] + h1[5]) + (h1[6] + h1[7]));
    z2[n0 + pp] = tot0 + tot1;
  }
}

// Screening v7 (r14-verified): 64 pts/block, 256 thr, B direct from L2 with
// register double-buffered prefetch. Chunk epilogue: exact prefix-min via one
// barrier (r9-verified superset).
__global__ __launch_bounds__(256, 4) void vq_screen(
    const float* __restrict__ z, const _Float16* __restrict__ Ef,
    const float* __restrict__ e2, const float* __restrict__ z2,
    int* __restrict__ gcnt, unsigned short* __restrict__ gcand) {
  extern __shared__ __align__(16) char smem[];
  // [0,32768) A; 32768 runminU[64]; 33024 cnt[64]; 33280 cand[64][16]
  unsigned* runminU = (unsigned*)(smem + 32768);
  int* cnt = (int*)(smem + 33024);
  unsigned short* cand = (unsigned short*)(smem + 33280);

  const int tid = threadIdx.x;
  const int blk = blockIdx.x;
  const int n0 = blk * 64;
  const int bb = blk >> 4;
  const int hw0 = (blk & 15) * 64;
  const float* zb = z + bb * 262144 + hw0;

  if (tid < 64) { runminU[tid] = 0x7F800000u; cnt[tid] = 0; }

  {  // A stage: convert z tile to f16, swizzled rows
    const int p = tid & 63, dh = tid >> 6;
    #pragma unroll
    for (int dq = 0; dq < 8; ++dq) {
      const int d0 = dh * 64 + dq * 8;
      f16x8 hv;
      #pragma unroll
      for (int j = 0; j < 8; ++j) hv[j] = (_Float16)zb[(d0 + j) * 1024 + p];
      *(f16x8*)&smem[p * 512 + ((d0 * 2) ^ ((p & 7) * 16))] = hv;
    }
  }

  const int l = tid & 63;
  const int ln = l & 15;
  const int q = l >> 4;
  const int wc = tid >> 6;        // wave: codes wc*64 .. +63 per chunk
  const int xr = (l & 7) * 16;

  float z2r[4][4];
  #pragma unroll
  for (int fi = 0; fi < 4; ++fi)
    #pragma unroll
    for (int rg = 0; rg < 4; ++rg)
      z2r[fi][rg] = z2[n0 + fi * 16 + q * 4 + rg];

  f32x4 acc[4][4];
  #pragma unroll
  for (int fi = 0; fi < 4; ++fi)
    #pragma unroll
    for (int fj = 0; fj < 4; ++fj) acc[fi][fj] = (f32x4){0.f, 0.f, 0.f, 0.f};

  __syncthreads();

  for (int cc = 0; cc < 4; ++cc) {
    const _Float16* Ebase = Ef + (cc * 256 + wc * 64 + ln) * 256 + q * 8;
    f16x8 bFb[2][4];
    #pragma unroll
    for (int fj = 0; fj < 4; ++fj)   // prologue: phase-0 B fragments
      bFb[0][fj] = *(const f16x8*)(Ebase + fj * 16 * 256);
    #pragma unroll
    for (int ph = 0; ph < 8; ++ph) {
      const int cur = ph & 1, nxt = cur ^ 1;
      if (ph < 7) {  // issue next phase's B loads before this phase's MFMAs
        #pragma unroll
        for (int fj = 0; fj < 4; ++fj)
          bFb[nxt][fj] = *(const f16x8*)(Ebase + fj * 16 * 256 + (ph + 1) * 32);
      }
      f16x8 aF[4];
      const int ab = (ph * 64 + q * 16) ^ xr;
      #pragma unroll
      for (int fi = 0; fi < 4; ++fi)
        aF[fi] = *(const f16x8*)&smem[(fi * 16 + ln) * 512 + ab];
      #pragma unroll
      for (int fi = 0; fi < 4; ++fi)
        #pragma unroll
        for (int fj = 0; fj < 4; ++fj)
          acc[fi][fj] = __builtin_amdgcn_mfma_f32_16x16x32_f16(
              aF[fi], bFb[cur][fj], acc[fi][fj], 0, 0, 0);
    }
    {  // chunk epilogue: exact prefix-min via one barrier
      const int cbase = cc * 256 + wc * 64 + ln;
      float e2v[4];
      #pragma unroll
      for (int fj = 0; fj < 4; ++fj) e2v[fj] = e2[cbase + fj * 16];
      #pragma unroll
      for (int fi = 0; fi < 4; ++fi) {
        #pragma unroll
        for (int rg = 0; rg < 4; ++rg) {
          float rm = 3.4e38f;
          #pragma unroll
          for (int fj = 0; fj < 4; ++fj)
            rm = fminf(rm, fmaf(-2.f, acc[fi][fj][rg], z2r[fi][rg] + e2v[fj]));
          rm = fminf(rm, __shfl_xor(rm, 1));
          rm = fminf(rm, __shfl_xor(rm, 2));
          rm = fminf(rm, __shfl_xor(rm, 4));
          rm = fminf(rm, __shfl_xor(rm, 8));
          if (ln == 0)
            atomicMin(&runminU[fi * 16 + q * 4 + rg], __float_as_uint(rm));
        }
      }
      __syncthreads();  // runminU now = true min over ALL codes up to chunk cc
      #pragma unroll
      for (int fi = 0; fi < 4; ++fi) {
        #pragma unroll
        for (int rg = 0; rg < 4; ++rg) {
          const int row = fi * 16 + q * 4 + rg;
          const float thr = __uint_as_float(runminU[row]) + VQ_W;
          #pragma unroll
          for (int fj = 0; fj < 4; ++fj) {
            const float sv = fmaf(-2.f, acc[fi][fj][rg], z2r[fi][rg] + e2v[fj]);
            if (sv <= thr) {
              const int slot = atomicAdd(&cnt[row], 1);
              if (slot < 16)
                cand[row * 16 + slot] = (unsigned short)(cbase + fj * 16);
            }
          }
        }
        #pragma unroll
        for (int fj = 0; fj < 4; ++fj) acc[fi][fj] = (f32x4){0.f, 0.f, 0.f, 0.f};
      }
    }
  }

  __syncthreads();
  if (tid < 64) gcnt[n0 + tid] = cnt[tid];
  {
    const int rr = tid >> 2, si = (tid & 3) * 4;
    *(uint2*)&gcand[(n0 + rr) * 16 + si] = *(const uint2*)&cand[rr * 16 + si];
  }
}

// vq_post v3: fused rescore + output + loss, 32 points/block (grid 2048),
// ALL VMEM float4-vectorized along hw (4 points per access).
// Phase R: z tile -> LDS zt[32][257] via float4 loads + scalar LDS scatter
//   (bit-identical zt content; r6-verified rescore chain; u64 atomicMin merge).
// Phase O: gather 32 emb rows -> rows[32][261] (float4), then per (4pts, d):
//   float4 z load, LDS q reads, df barrier, float4 store, f64 loss.
__global__ __launch_bounds__(256) void vq_post(
    const float* __restrict__ z, const float* __restrict__ emb,
    const float* __restrict__ e2, const float* __restrict__ z2,
    const int* __restrict__ gcnt, const unsigned short* __restrict__ gcand,
    float* __restrict__ out, double* __restrict__ acc) {
  extern __shared__ __align__(16) char psmem[];
  // union @0: zt[32][257] f32 (32896B) | rows[32][261] f32 (33408B)
  // 33408 wid[32] int (128B) ; 33536 best[32] u64 (256B)
  float* zt = (float*)psmem;
  float* rows = (float*)psmem;
  int* wid = (int*)(psmem + 33408);
  unsigned long long* best = (unsigned long long*)(psmem + 33536);

  const int tid = threadIdx.x;
  const int pg = tid & 7;    // point group: points pg*4..pg*4+3
  const int ds = tid >> 3;   // d-slice 0..31: d = ds*8..ds*8+7
  const int w8 = tid >> 5;   // 0..7 (rescore candidate lane)
  const int l = tid & 31;    // point (rescore)
  const int n0 = blockIdx.x << 5;
  const int bb = n0 >> 10, hw0 = n0 & 1023;
  const int n = n0 + l;

  const int c = gcnt[n];
  const bool need = __any(c >= 2);  // wave-uniform: every wave sees l=0..31

  if (need) {  // stage z tile: float4 along hw, scalar scatter to zt rows
    const float* zb = z + bb * 262144 + hw0 + pg * 4;
    #pragma unroll
    for (int jj = 0; jj < 8; ++jj) {
      const int d = ds * 8 + jj;
      const float4 v = *(const float4*)&zb[d * 1024];
      zt[(pg * 4 + 0) * 257 + d] = v.x;
      zt[(pg * 4 + 1) * 257 + d] = v.y;
      zt[(pg * 4 + 2) * 257 + d] = v.z;
      zt[(pg * 4 + 3) * 257 + d] = v.w;
    }
  }
  if (tid < 32) best[tid] = ~0ULL;
  __syncthreads();

  if (need && c >= 2) {
    const float z2n = z2[n];
    const float* zrow = &zt[l * 257];
    if (c <= 16) {
      for (int s = w8; s < c; s += 8) {
        const int k = gcand[n * 16 + s];
        const float* ep = emb + k * 256;
        float a = 0.f;
        #pragma unroll 4
        for (int d = 0; d < 256; ++d) a = fmaf(zrow[d], ep[d], a);
        const float sv = fmaf(-2.f, a, z2n + e2[k]);
        const unsigned long long key =
            ((unsigned long long)__float_as_uint(sv) << 10) | (unsigned)k;
        atomicMin(&best[l], key);
      }
    } else {  // overflow fallback: exact full scan
      for (int k = w8; k < 1024; k += 8) {
        const float* ep = emb + k * 256;
        float a = 0.f;
        #pragma unroll 4
        for (int d = 0; d < 256; ++d) a = fmaf(zrow[d], ep[d], a);
        const float sv = fmaf(-2.f, a, z2n + e2[k]);
        const unsigned long long key =
            ((unsigned long long)__float_as_uint(sv) << 10) | (unsigned)k;
        atomicMin(&best[l], key);
      }
    }
  }
  __syncthreads();
  if (tid < 32) {
    const int cc = gcnt[n0 + tid];
    const int v = (cc == 1) ? (int)gcand[(n0 + tid) * 16]
                            : (int)(best[tid] & 1023ULL);
    wid[tid] = v;
    out[16777217 + n0 + tid] = (float)v;
  }
  __syncthreads();

  // Phase O gather: 32 emb rows -> rows[32][261], float4, coalesced per row.
  {
    const int r = tid >> 3;  // row 0..31
    const float* er = emb + wid[r] * 256;
    #pragma unroll
    for (int k = 0; k < 8; ++k) {
      const int c4 = pg + 8 * k;  // float4 index 0..63
      *(float4*)&rows[r * 261 + c4 * 4] = *(const float4*)&er[c4 * 4];
    }
  }
  __syncthreads();

  // Phase O out: per (4-pt group, d): float4 z, LDS q, float4 store, f64 loss.
  const float* zb = z + bb * 262144 + hw0 + pg * 4;
  float* ob = out + bb * 262144 + hw0 + pg * 4;
  double ls = 0.0;
  #pragma unroll
  for (int jj = 0; jj < 8; ++jj) {
    const int d = ds * 8 + jj;
    const float4 zv = *(const float4*)&zb[d * 1024];
    float4 qv;
    qv.x = rows[(pg * 4 + 0) * 261 + d];
    qv.y = rows[(pg * 4 + 1) * 261 + d];
    qv.z = rows[(pg * 4 + 2) * 261 + d];
    qv.w = rows[(pg * 4 + 3) * 261 + d];
    float dx = qv.x - zv.x, dy = qv.y - zv.y, dz = qv.z - zv.z, dw = qv.w - zv.w;
    asm volatile("" : "+v"(dx), "+v"(dy), "+v"(dz), "+v"(dw));
    float4 ov;
    ov.x = zv.x + dx; ov.y = zv.y + dy; ov.z = zv.z + dz; ov.w = zv.w + dw;
    *(float4*)&ob[d * 1024] = ov;
    ls += (double)dx * dx + (double)dy * dy + (double)dz * dz + (double)dw * dw;
  }
  #pragma unroll
  for (int off = 32; off > 0; off >>= 1) ls += __shfl_down(ls, off);
  if ((tid & 63) == 0) atomicAdd(acc, ls);
}

__global__ void vq_fin(const double* __restrict__ acc, float* __restrict__ out) {
  if (threadIdx.x == 0)
    out[16777216] = (float)(1.25 * (*acc) * (1.0 / 16777216.0));
}

extern "C" void kernel_launch(void* const* d_in, const int* in_sizes, int n_in,
                              void* d_out, int out_size, void* d_ws, size_t ws_size,
                              hipStream_t stream) {
  const float* z = (const float*)d_in[0];
  const float* emb = (const float*)d_in[1];
  float* out = (float*)d_out;
  char* ws = (char*)d_ws;
  double* acc = (double*)(ws);
  float* e2 = (float*)(ws + 262208);
  float* z2 = (float*)(ws + 266304);
  int* gcnt = (int*)(ws + 528448);
  unsigned short* gcand = (unsigned short*)(ws + 790592);
  _Float16* Ef = (_Float16*)(ws + 2887744);

  hipFuncSetAttribute(reinterpret_cast<const void*>(vq_screen),
                      hipFuncAttributeMaxDynamicSharedMemorySize, SCR_LDS_BYTES);
  hipFuncSetAttribute(reinterpret_cast<const void*>(vq_post),
                      hipFuncAttributeMaxDynamicSharedMemorySize, POST_LDS_BYTES);

  hipMemsetAsync(ws, 0, 64, stream);
  vq_pre<<<5120, 256, 0, stream>>>(emb, z, Ef, e2, z2);
  vq_screen<<<1024, 256, SCR_LDS_BYTES, stream>>>(z, Ef, e2, z2, gcnt, gcand);
  vq_post<<<2048, 256, POST_LDS_BYTES, stream>>>(z, emb, e2, z2, gcnt, gcand,
                                                 out, acc);
  vq_fin<<<1, 64, 0, stream>>>(acc, out);
}

// Round 17
// 273.089 us; speedup vs baseline: 1.1120x; 1.0649x over previous
//
#include <hip/hip_runtime.h>

// VectorQuantizer on MI355X — round 17: vq_post v4 — explicit register staging
// (8 float4 loads in flight per thread; VGPR cap 128 via launch_bounds).
// z: (64,256,32,32) f32; emb: (1024,256) f32.
// out (f32): [0,16777216) z_q_out | [16777216] loss | [16777217,+65536) indices
//
// ws layout (bytes):
//   0        double   loss_acc                 (memset 0)
//   262208   float    e2[1024]                 (numpy-pairwise fp32)
//   266304   float    z2[65536]                (numpy-pairwise fp32)
//   528448   int      gcnt[65536]
//   790592   ushort   gcand[65536*16]
//   2887744  _Float16 Ef[1024*256]             (f16 RNE copy of emb)

typedef _Float16 f16x8 __attribute__((ext_vector_type(8)));
typedef float f32x4 __attribute__((ext_vector_type(4)));

#define VQ_W 1.5e-3f
#define SCR_LDS_BYTES 35328
#define POST_LDS_BYTES 33792

// fl32(v*v) with a barrier so the product cannot be contracted into a later add.
__device__ __forceinline__ float sq_rnd(float v) {
  float y = v * v;
  asm volatile("" : "+v"(y));
  return y;
}

// numpy pairwise_sum over 256 fp32 squared terms (8-accumulator blocks of 128).
__device__ float np_pw256_sq(const float* base, int stride) {
  float tot0, tot1;
  {
    const float* a = base;
    float r[8];
    #pragma unroll
    for (int j = 0; j < 8; ++j) r[j] = sq_rnd(a[j * stride]);
    #pragma unroll 1
    for (int i = 8; i < 128; i += 8) {
      #pragma unroll
      for (int j = 0; j < 8; ++j) r[j] += sq_rnd(a[(i + j) * stride]);
    }
    tot0 = ((r[0] + r[1]) + (r[2] + r[3])) + ((r[4] + r[5]) + (r[6] + r[7]));
  }
  {
    const float* a = base + 128 * stride;
    float r[8];
    #pragma unroll
    for (int j = 0; j < 8; ++j) r[j] = sq_rnd(a[j * stride]);
    #pragma unroll 1
    for (int i = 8; i < 128; i += 8) {
      #pragma unroll
      for (int j = 0; j < 8; ++j) r[j] += sq_rnd(a[(i + j) * stride]);
    }
    tot1 = ((r[0] + r[1]) + (r[2] + r[3])) + ((r[4] + r[5]) + (r[6] + r[7]));
  }
  return tot0 + tot1;
}

// Fused preprocessing: blocks [0,1024) = emb->f16 + e2 (r3-verified);
// blocks [1024,5120) = z2 chain-split (r11-verified, bit-exact np order).
__global__ __launch_bounds__(256) void vq_pre(const float* __restrict__ emb,
                                              const float* __restrict__ z,
                                              _Float16* __restrict__ Ef,
                                              float* __restrict__ e2,
                                              float* __restrict__ z2) {
  __shared__ float sm[256];
  const int tid = threadIdx.x;
  if (blockIdx.x < 1024) {
    const int g = blockIdx.x * 256 + tid;  // 0..262143
    Ef[g] = (_Float16)emb[g];              // RNE v_cvt_f16_f32
    if (g < 1024) e2[g] = np_pw256_sq(emb + g * 256, 1);
    return;
  }
  const int blk = blockIdx.x - 1024;       // 0..4095
  const int p = tid & 15;
  const int c = tid >> 4;
  const int n0 = blk * 16;
  const int n = n0 + p;
  const int bb = n >> 10, hw = n & 1023;
  const float* zp = z + bb * 262144 + hw;
  const int dbase = (c >> 3) * 128 + (c & 7);
  float r = sq_rnd(zp[dbase * 1024]);
  #pragma unroll
  for (int i = 1; i < 16; ++i) r += sq_rnd(zp[(dbase + 8 * i) * 1024]);
  sm[c * 16 + p] = r;
  __syncthreads();
  if (tid < 16) {
    const int pp = tid;
    float h0[8], h1[8];
    #pragma unroll
    for (int j = 0; j < 8; ++j) {
      h0[j] = sm[j * 16 + pp];
      h1[j] = sm[(8 + j) * 16 + pp];
    }
    const float tot0 = ((h0[0] + h0[1]) + (h0[2] + h0[3])) +
                       ((h0[4] + h0[5]) + (h0[6] + h0[7]));
    const float tot1 = ((h1[0] + h1[1]) + (h1[2] + h1[3])) +
                       ((h1[4] + h1[5]) + (h1[6] + h1[7]));
    z2[n0 + pp] = tot0 + tot1;
  }
}

// Screening v7 (r14-verified): 64 pts/block, 256 thr, B direct from L2 with
// register double-buffered prefetch. Chunk epilogue: exact prefix-min via one
// barrier (r9-verified superset).
__global__ __launch_bounds__(256, 4) void vq_screen(
    const float* __restrict__ z, const _Float16* __restrict__ Ef,
    const float* __restrict__ e2, const float* __restrict__ z2,
    int* __restrict__ gcnt, unsigned short* __restrict__ gcand) {
  extern __shared__ __align__(16) char smem[];
  // [0,32768) A; 32768 runminU[64]; 33024 cnt[64]; 33280 cand[64][16]
  unsigned* runminU = (unsigned*)(smem + 32768);
  int* cnt = (int*)(smem + 33024);
  unsigned short* cand = (unsigned short*)(smem + 33280);

  const int tid = threadIdx.x;
  const int blk = blockIdx.x;
  const int n0 = blk * 64;
  const int bb = blk >> 4;
  const int hw0 = (blk & 15) * 64;
  const float* zb = z + bb * 262144 + hw0;

  if (tid < 64) { runminU[tid] = 0x7F800000u; cnt[tid] = 0; }

  {  // A stage: convert z tile to f16, swizzled rows
    const int p = tid & 63, dh = tid >> 6;
    #pragma unroll
    for (int dq = 0; dq < 8; ++dq) {
      const int d0 = dh * 64 + dq * 8;
      f16x8 hv;
      #pragma unroll
      for (int j = 0; j < 8; ++j) hv[j] = (_Float16)zb[(d0 + j) * 1024 + p];
      *(f16x8*)&smem[p * 512 + ((d0 * 2) ^ ((p & 7) * 16))] = hv;
    }
  }

  const int l = tid & 63;
  const int ln = l & 15;
  const int q = l >> 4;
  const int wc = tid >> 6;        // wave: codes wc*64 .. +63 per chunk
  const int xr = (l & 7) * 16;

  float z2r[4][4];
  #pragma unroll
  for (int fi = 0; fi < 4; ++fi)
    #pragma unroll
    for (int rg = 0; rg < 4; ++rg)
      z2r[fi][rg] = z2[n0 + fi * 16 + q * 4 + rg];

  f32x4 acc[4][4];
  #pragma unroll
  for (int fi = 0; fi < 4; ++fi)
    #pragma unroll
    for (int fj = 0; fj < 4; ++fj) acc[fi][fj] = (f32x4){0.f, 0.f, 0.f, 0.f};

  __syncthreads();

  for (int cc = 0; cc < 4; ++cc) {
    const _Float16* Ebase = Ef + (cc * 256 + wc * 64 + ln) * 256 + q * 8;
    f16x8 bFb[2][4];
    #pragma unroll
    for (int fj = 0; fj < 4; ++fj)   // prologue: phase-0 B fragments
      bFb[0][fj] = *(const f16x8*)(Ebase + fj * 16 * 256);
    #pragma unroll
    for (int ph = 0; ph < 8; ++ph) {
      const int cur = ph & 1, nxt = cur ^ 1;
      if (ph < 7) {  // issue next phase's B loads before this phase's MFMAs
        #pragma unroll
        for (int fj = 0; fj < 4; ++fj)
          bFb[nxt][fj] = *(const f16x8*)(Ebase + fj * 16 * 256 + (ph + 1) * 32);
      }
      f16x8 aF[4];
      const int ab = (ph * 64 + q * 16) ^ xr;
      #pragma unroll
      for (int fi = 0; fi < 4; ++fi)
        aF[fi] = *(const f16x8*)&smem[(fi * 16 + ln) * 512 + ab];
      #pragma unroll
      for (int fi = 0; fi < 4; ++fi)
        #pragma unroll
        for (int fj = 0; fj < 4; ++fj)
          acc[fi][fj] = __builtin_amdgcn_mfma_f32_16x16x32_f16(
              aF[fi], bFb[cur][fj], acc[fi][fj], 0, 0, 0);
    }
    {  // chunk epilogue: exact prefix-min via one barrier
      const int cbase = cc * 256 + wc * 64 + ln;
      float e2v[4];
      #pragma unroll
      for (int fj = 0; fj < 4; ++fj) e2v[fj] = e2[cbase + fj * 16];
      #pragma unroll
      for (int fi = 0; fi < 4; ++fi) {
        #pragma unroll
        for (int rg = 0; rg < 4; ++rg) {
          float rm = 3.4e38f;
          #pragma unroll
          for (int fj = 0; fj < 4; ++fj)
            rm = fminf(rm, fmaf(-2.f, acc[fi][fj][rg], z2r[fi][rg] + e2v[fj]));
          rm = fminf(rm, __shfl_xor(rm, 1));
          rm = fminf(rm, __shfl_xor(rm, 2));
          rm = fminf(rm, __shfl_xor(rm, 4));
          rm = fminf(rm, __shfl_xor(rm, 8));
          if (ln == 0)
            atomicMin(&runminU[fi * 16 + q * 4 + rg], __float_as_uint(rm));
        }
      }
      __syncthreads();  // runminU now = true min over ALL codes up to chunk cc
      #pragma unroll
      for (int fi = 0; fi < 4; ++fi) {
        #pragma unroll
        for (int rg = 0; rg < 4; ++rg) {
          const int row = fi * 16 + q * 4 + rg;
          const float thr = __uint_as_float(runminU[row]) + VQ_W;
          #pragma unroll
          for (int fj = 0; fj < 4; ++fj) {
            const float sv = fmaf(-2.f, acc[fi][fj][rg], z2r[fi][rg] + e2v[fj]);
            if (sv <= thr) {
              const int slot = atomicAdd(&cnt[row], 1);
              if (slot < 16)
                cand[row * 16 + slot] = (unsigned short)(cbase + fj * 16);
            }
          }
        }
        #pragma unroll
        for (int fj = 0; fj < 4; ++fj) acc[fi][fj] = (f32x4){0.f, 0.f, 0.f, 0.f};
      }
    }
  }

  __syncthreads();
  if (tid < 64) gcnt[n0 + tid] = cnt[tid];
  {
    const int rr = tid >> 2, si = (tid & 3) * 4;
    *(uint2*)&gcand[(n0 + rr) * 16 + si] = *(const uint2*)&cand[rr * 16 + si];
  }
}

// vq_post v4: fused rescore + output + loss, 32 points/block (grid 2048).
// ALL global loads explicitly register-staged (8 float4 outstanding/thread):
//   stage zS[8] -> LDS scatter; gather ev[8] -> rows; out zv[8] -> compute.
// launch_bounds(256,4): VGPR cap 128, 4 blocks/CU at 33.8KB LDS.
// Arithmetic bit-identical to r16 (r6-verified rescore chain; df barrier).
__global__ __launch_bounds__(256, 4) void vq_post(
    const float* __restrict__ z, const float* __restrict__ emb,
    const float* __restrict__ e2, const float* __restrict__ z2,
    const int* __restrict__ gcnt, const unsigned short* __restrict__ gcand,
    float* __restrict__ out, double* __restrict__ acc) {
  extern __shared__ __align__(16) char psmem[];
  // union @0: zt[32][257] f32 (32896B) | rows[32][261] f32 (33408B)
  // 33408 wid[32] int (128B) ; 33536 best[32] u64 (256B)
  float* zt = (float*)psmem;
  float* rows = (float*)psmem;
  int* wid = (int*)(psmem + 33408);
  unsigned long long* best = (unsigned long long*)(psmem + 33536);

  const int tid = threadIdx.x;
  const int pg = tid & 7;    // point group: points pg*4..pg*4+3
  const int ds = tid >> 3;   // d-slice 0..31: d = ds*8..ds*8+7
  const int w8 = tid >> 5;   // 0..7 (rescore candidate lane)
  const int l = tid & 31;    // point (rescore)
  const int n0 = blockIdx.x << 5;
  const int bb = n0 >> 10, hw0 = n0 & 1023;
  const int n = n0 + l;

  const int c = gcnt[n];
  const bool need = __any(c >= 2);  // wave-uniform: every wave sees l=0..31

  if (need) {  // stage z tile: 8 float4 loads issued together, then scatter
    const float* zb = z + bb * 262144 + hw0 + pg * 4;
    float4 zS[8];
    #pragma unroll
    for (int jj = 0; jj < 8; ++jj) zS[jj] = *(const float4*)&zb[(ds * 8 + jj) * 1024];
    #pragma unroll
    for (int jj = 0; jj < 8; ++jj) {
      const int d = ds * 8 + jj;
      zt[(pg * 4 + 0) * 257 + d] = zS[jj].x;
      zt[(pg * 4 + 1) * 257 + d] = zS[jj].y;
      zt[(pg * 4 + 2) * 257 + d] = zS[jj].z;
      zt[(pg * 4 + 3) * 257 + d] = zS[jj].w;
    }
  }
  if (tid < 32) best[tid] = ~0ULL;
  __syncthreads();

  if (need && c >= 2) {
    const float z2n = z2[n];
    const float* zrow = &zt[l * 257];
    if (c <= 16) {
      for (int s = w8; s < c; s += 8) {
        const int k = gcand[n * 16 + s];
        const float4* ep4 = (const float4*)(emb + k * 256);
        float a = 0.f;
        #pragma unroll 8
        for (int d4 = 0; d4 < 64; ++d4) {  // float4 emb loads; chain order exact
          const float4 ev = ep4[d4];
          a = fmaf(zrow[d4 * 4 + 0], ev.x, a);
          a = fmaf(zrow[d4 * 4 + 1], ev.y, a);
          a = fmaf(zrow[d4 * 4 + 2], ev.z, a);
          a = fmaf(zrow[d4 * 4 + 3], ev.w, a);
        }
        const float sv = fmaf(-2.f, a, z2n + e2[k]);
        const unsigned long long key =
            ((unsigned long long)__float_as_uint(sv) << 10) | (unsigned)k;
        atomicMin(&best[l], key);
      }
    } else {  // overflow fallback: exact full scan
      for (int k = w8; k < 1024; k += 8) {
        const float4* ep4 = (const float4*)(emb + k * 256);
        float a = 0.f;
        #pragma unroll 8
        for (int d4 = 0; d4 < 64; ++d4) {
          const float4 ev = ep4[d4];
          a = fmaf(zrow[d4 * 4 + 0], ev.x, a);
          a = fmaf(zrow[d4 * 4 + 1], ev.y, a);
          a = fmaf(zrow[d4 * 4 + 2], ev.z, a);
          a = fmaf(zrow[d4 * 4 + 3], ev.w, a);
        }
        const float sv = fmaf(-2.f, a, z2n + e2[k]);
        const unsigned long long key =
            ((unsigned long long)__float_as_uint(sv) << 10) | (unsigned)k;
        atomicMin(&best[l], key);
      }
    }
  }
  __syncthreads();
  if (tid < 32) {
    const int cc = gcnt[n0 + tid];
    const int v = (cc == 1) ? (int)gcand[(n0 + tid) * 16]
                            : (int)(best[tid] & 1023ULL);
    wid[tid] = v;
    out[16777217 + n0 + tid] = (float)v;
  }
  __syncthreads();

  // Phase O gather: 8 float4 from emb row (L2) staged, then LDS writes.
  {
    const int r = tid >> 3;  // row 0..31
    const float* er = emb + wid[r] * 256;
    float4 ev[8];
    #pragma unroll
    for (int k = 0; k < 8; ++k) ev[k] = *(const float4*)&er[(pg + 8 * k) * 4];
    #pragma unroll
    for (int k = 0; k < 8; ++k)
      *(float4*)&rows[r * 261 + (pg + 8 * k) * 4] = ev[k];
  }
  __syncthreads();

  // Phase O out: 8 float4 z loads staged, then per jj: LDS q, store, f64 loss.
  const float* zb = z + bb * 262144 + hw0 + pg * 4;
  float* ob = out + bb * 262144 + hw0 + pg * 4;
  float4 zv[8];
  #pragma unroll
  for (int jj = 0; jj < 8; ++jj) zv[jj] = *(const float4*)&zb[(ds * 8 + jj) * 1024];
  double ls = 0.0;
  #pragma unroll
  for (int jj = 0; jj < 8; ++jj) {
    const int d = ds * 8 + jj;
    float4 qv;
    qv.x = rows[(pg * 4 + 0) * 261 + d];
    qv.y = rows[(pg * 4 + 1) * 261 + d];
    qv.z = rows[(pg * 4 + 2) * 261 + d];
    qv.w = rows[(pg * 4 + 3) * 261 + d];
    float dx = qv.x - zv[jj].x, dy = qv.y - zv[jj].y;
    float dz = qv.z - zv[jj].z, dw = qv.w - zv[jj].w;
    asm volatile("" : "+v"(dx), "+v"(dy), "+v"(dz), "+v"(dw));
    float4 ov;
    ov.x = zv[jj].x + dx; ov.y = zv[jj].y + dy;
    ov.z = zv[jj].z + dz; ov.w = zv[jj].w + dw;
    *(float4*)&ob[d * 1024] = ov;
    ls += (double)dx * dx + (double)dy * dy + (double)dz * dz + (double)dw * dw;
  }
  #pragma unroll
  for (int off = 32; off > 0; off >>= 1) ls += __shfl_down(ls, off);
  if ((tid & 63) == 0) atomicAdd(acc, ls);
}

__global__ void vq_fin(const double* __restrict__ acc, float* __restrict__ out) {
  if (threadIdx.x == 0)
    out[16777216] = (float)(1.25 * (*acc) * (1.0 / 16777216.0));
}

extern "C" void kernel_launch(void* const* d_in, const int* in_sizes, int n_in,
                              void* d_out, int out_size, void* d_ws, size_t ws_size,
                              hipStream_t stream) {
  const float* z = (const float*)d_in[0];
  const float* emb = (const float*)d_in[1];
  float* out = (float*)d_out;
  char* ws = (char*)d_ws;
  double* acc = (double*)(ws);
  float* e2 = (float*)(ws + 262208);
  float* z2 = (float*)(ws + 266304);
  int* gcnt = (int*)(ws + 528448);
  unsigned short* gcand = (unsigned short*)(ws + 790592);
  _Float16* Ef = (_Float16*)(ws + 2887744);

  hipFuncSetAttribute(reinterpret_cast<const void*>(vq_screen),
                      hipFuncAttributeMaxDynamicSharedMemorySize, SCR_LDS_BYTES);
  hipFuncSetAttribute(reinterpret_cast<const void*>(vq_post),
                      hipFuncAttributeMaxDynamicSharedMemorySize, POST_LDS_BYTES);

  hipMemsetAsync(ws, 0, 64, stream);
  vq_pre<<<5120, 256, 0, stream>>>(emb, z, Ef, e2, z2);
  vq_screen<<<1024, 256, SCR_LDS_BYTES, stream>>>(z, Ef, e2, z2, gcnt, gcand);
  vq_post<<<2048, 256, POST_LDS_BYTES, stream>>>(z, emb, e2, z2, gcnt, gcand,
                                                 out, acc);
  vq_fin<<<1, 64, 0, stream>>>(acc, out);
}